// Round 5
// baseline (226.928 us; speedup 1.0000x reference)
//
#include <hip/hip_runtime.h>

// LayerStacks round 5: R3 structure (bucket-sorted, 64-aligned segments,
// wave-uniform bucket -> scalar weight loads) + named-register depth-3
// software pipeline for the per-lane x gather (no arrays/pointer swaps ->
// stays in VGPRs), slimmer prep (4 kernels + memset), bucket encoded in perm.
//
// d_ws layout:
//   floats [0 .. WBLOB)             packed weights, 6 buckets x BSTRIDE
//   ints   [WBLOB .. WBLOB+16)      cnt[6] (pad 8), cursor[6] (pad 8)
//   ints   [WBLOB+16 .. +16+padcap) perm: (bucket<<26)|sample, -1 = pad

#define NB 6
#define BSTRIDE 4544
#define O_W1T   0      // [c=0..31][j=0..7][q=0..3] c-major W1b quads (32 floats/step)
#define O_WPAT  1024   // same for W1pa
#define O_MISC  2048   // [0:8) W1b[:,128], [8:16) W1pa[:,128], [16:24) b1b, [24:32) b1pa
#define O_W2    2080   // [64][32] row-major
#define O_WOUT  4128   // [320]
#define O_B2    4448   // [64]
#define O_BOUT  4512   // [1]
#define WBLOB   (NB * BSTRIDE)

// ---------------- init+hist: pack weights, histogram ply ---------------------
// (wsI[0..16) zeroed by hipMemsetAsync before this kernel)
__global__ __launch_bounds__(1024)
void k_init_hist(const float* __restrict__ W1b, const float* __restrict__ b1b,
                 const float* __restrict__ W1pa, const float* __restrict__ b1pa,
                 const float* __restrict__ W2, const float* __restrict__ b2,
                 const float* __restrict__ Wout, const float* __restrict__ bout,
                 const int* __restrict__ ply,
                 float* __restrict__ wsF, int* __restrict__ wsI, int B)
{
    __shared__ int lh[NB];
    const int tid = threadIdx.x;
    if (tid < NB) lh[tid] = 0;
    __syncthreads();

    const int i0 = blockIdx.x * 1024 + tid;
    const int stride = gridDim.x * 1024;

    if (i0 < B) atomicAdd(&lh[ply[i0] / 10], 1);

    // W1 c-major quads
    for (int e = i0; e < NB * 1024; e += stride) {
        int b = e >> 10, r = e & 1023;
        int c = r >> 5, j = (r >> 2) & 7, q = r & 3;
        int src = b * 1032 + j * 129 + c * 4 + q;
        wsF[b * BSTRIDE + O_W1T + r]  = W1b[src];
        wsF[b * BSTRIDE + O_WPAT + r] = W1pa[src];
    }
    for (int e = i0; e < NB * 8; e += stride) {
        int b = e >> 3, j = e & 7;
        wsF[b * BSTRIDE + O_MISC + 0  + j] = W1b [b * 1032 + j * 129 + 128];
        wsF[b * BSTRIDE + O_MISC + 8  + j] = W1pa[b * 1032 + j * 129 + 128];
        wsF[b * BSTRIDE + O_MISC + 16 + j] = b1b[e];
        wsF[b * BSTRIDE + O_MISC + 24 + j] = b1pa[e];
    }
    for (int e = i0; e < NB * 2048; e += stride) {
        int b = e >> 11, r = e & 2047;
        wsF[b * BSTRIDE + O_W2 + r] = W2[e];
    }
    for (int e = i0; e < NB * 320; e += stride) {
        int b = e / 320, r = e - b * 320;
        wsF[b * BSTRIDE + O_WOUT + r] = Wout[e];
    }
    for (int e = i0; e < NB * 64; e += stride) {
        int b = e >> 6, r = e & 63;
        wsF[b * BSTRIDE + O_B2 + r] = b2[e];
    }
    for (int e = i0; e < NB; e += stride)
        wsF[e * BSTRIDE + O_BOUT] = bout[e];

    __syncthreads();
    if (tid < NB) atomicAdd(&wsI[tid], lh[tid]);
}

// ---------------- scan: 64-aligned bases + write pad entries -----------------
__global__ void k_scan(int* __restrict__ wsI, int B) {
    if (threadIdx.x != 0) return;
    int* perm = wsI + 16;
    const int padcap = B + NB * 64;
    int base = 0;
    for (int b = 0; b < NB; ++b) {
        wsI[8 + b] = base;
        const int cnt = wsI[b];
        const int end = base + cnt;
        const int cend = base + ((cnt + 63) & ~63);
        for (int i = end; i < cend; ++i) perm[i] = -1;
        base = cend;
    }
    for (int i = base; i < padcap; ++i) perm[i] = -1;
}

// ---------------- scatter: perm = (b<<26)|s ----------------------------------
__global__ __launch_bounds__(1024)
void k_scatter(const int* __restrict__ ply, int* __restrict__ wsI, int B) {
    __shared__ int lh[NB];
    __shared__ int lbase[NB];
    int* cursor = wsI + 8;
    int* perm   = wsI + 16;
    const int tid = threadIdx.x;
    if (tid < NB) lh[tid] = 0;
    __syncthreads();
    const int s = blockIdx.x * 1024 + tid;
    int b = 0, lpos = 0;
    if (s < B) { b = ply[s] / 10; lpos = atomicAdd(&lh[b], 1); }
    __syncthreads();
    if (tid < NB) lbase[tid] = atomicAdd(&cursor[tid], lh[tid]);
    __syncthreads();
    if (s < B) perm[lbase[b] + lpos] = s | (b << 26);
}

// ---------------- per-step FMA helper ----------------------------------------
__device__ __forceinline__ void step_fma(const float4 x, const float* __restrict__ wc,
                                         const float* __restrict__ wo,
                                         float* __restrict__ acc, float& aout)
{
    #pragma unroll
    for (int j = 0; j < 8; ++j) {
        const float4 w = *reinterpret_cast<const float4*>(wc + j * 4);
        acc[j] += w.x * x.x + w.y * x.y + w.z * x.z + w.w * x.w;
    }
    const float4 o = *reinterpret_cast<const float4*>(wo);
    aout += o.x * x.x + o.y * x.y + o.z * x.z + o.w * x.w;
}

// ---------------- main -------------------------------------------------------
__global__ __launch_bounds__(256, 4)
void layerstacks_main(const float* __restrict__ x_base,
                      const float* __restrict__ x_pa,
                      const float* __restrict__ mobility,
                      const float* __restrict__ wsF,
                      const int*   __restrict__ wsI,
                      float* __restrict__ out, int B)
{
    const int padcap = B + NB * 64;
    const int pos = blockIdx.x * 256 + threadIdx.x;
    const int* perm = wsI + 16;

    int e = (pos < padcap) ? perm[pos] : -1;
    const int e0 = __builtin_amdgcn_readfirstlane(e);
    if (e0 < 0) return;                              // whole wave padding

    const int bu = e0 >> 26;                         // wave-uniform bucket
    const float* __restrict__ wp = wsF + bu * BSTRIDE;

    const bool valid = (e >= 0);
    const int s  = e & 0x03FFFFFF;
    const int su = valid ? s : (e0 & 0x03FFFFFF);

    const float4* __restrict__ xb4 = reinterpret_cast<const float4*>(x_base + (size_t)su * 128);
    const float4* __restrict__ xp4 = reinterpret_cast<const float4*>(x_pa   + (size_t)su * 128);

    const float mob = fminf(mobility[su] * (7.0f / 255.0f), 1.0f);

    float acc1[16];
    #pragma unroll
    for (int j = 0; j < 8; ++j)
        acc1[j]     = wp[O_MISC + 16 + j] + wp[O_MISC + 0 + j] * mob;
    #pragma unroll
    for (int j = 0; j < 8; ++j)
        acc1[8 + j] = wp[O_MISC + 24 + j] + wp[O_MISC + 8 + j] * mob;

    float accA = 0.0f, accP = 0.0f;                  // independent chains

    // ---- depth-3 software pipeline over 16 chunks (4 float4 each) ----------
    // chunk c: c<8 -> x_base cols [c*16 .. c*16+15], else x_pa
    float4 P0, P1, P2, P3, Q0, Q1, Q2, Q3, R0, R1, R2, R3;

#define LOADC(c, X0, X1, X2, X3) do {                                          \
        const float4* p_ = ((c) < 8) ? (xb4 + (c) * 4) : (xp4 + ((c) - 8) * 4);\
        X0 = p_[0]; X1 = p_[1]; X2 = p_[2]; X3 = p_[3];                        \
    } while (0)

#define DOCHUNK(c, X0, X1, X2, X3) do {                                        \
        const float* wb_ = wp + (((c) < 8) ? O_W1T : O_WPAT) + ((c) & 7) * 128;\
        const float* wo_ = wp + O_WOUT +                                       \
            (((c) < 8) ? (64 + (c) * 16) : (192 + ((c) - 8) * 16));            \
        float* ap_ = acc1 + (((c) < 8) ? 0 : 8);                               \
        float& ao_ = ((c) < 8) ? accA : accP;                                  \
        step_fma(X0, wb_ + 0,  wo_ + 0,  ap_, ao_);                            \
        step_fma(X1, wb_ + 32, wo_ + 4,  ap_, ao_);                            \
        step_fma(X2, wb_ + 64, wo_ + 8,  ap_, ao_);                            \
        step_fma(X3, wb_ + 96, wo_ + 12, ap_, ao_);                            \
    } while (0)

    LOADC(0, P0, P1, P2, P3);
    LOADC(1, Q0, Q1, Q2, Q3);
    LOADC(2, R0, R1, R2, R3);

    DOCHUNK(0,  P0, P1, P2, P3); LOADC(3,  P0, P1, P2, P3);
    DOCHUNK(1,  Q0, Q1, Q2, Q3); LOADC(4,  Q0, Q1, Q2, Q3);
    DOCHUNK(2,  R0, R1, R2, R3); LOADC(5,  R0, R1, R2, R3);
    DOCHUNK(3,  P0, P1, P2, P3); LOADC(6,  P0, P1, P2, P3);
    DOCHUNK(4,  Q0, Q1, Q2, Q3); LOADC(7,  Q0, Q1, Q2, Q3);
    DOCHUNK(5,  R0, R1, R2, R3); LOADC(8,  R0, R1, R2, R3);
    DOCHUNK(6,  P0, P1, P2, P3); LOADC(9,  P0, P1, P2, P3);
    DOCHUNK(7,  Q0, Q1, Q2, Q3); LOADC(10, Q0, Q1, Q2, Q3);
    DOCHUNK(8,  R0, R1, R2, R3); LOADC(11, R0, R1, R2, R3);
    DOCHUNK(9,  P0, P1, P2, P3); LOADC(12, P0, P1, P2, P3);
    DOCHUNK(10, Q0, Q1, Q2, Q3); LOADC(13, Q0, Q1, Q2, Q3);
    DOCHUNK(11, R0, R1, R2, R3); LOADC(14, R0, R1, R2, R3);
    DOCHUNK(12, P0, P1, P2, P3); LOADC(15, P0, P1, P2, P3);
    DOCHUNK(13, Q0, Q1, Q2, Q3);
    DOCHUNK(14, R0, R1, R2, R3);
    DOCHUNK(15, P0, P1, P2, P3);

#undef LOADC
#undef DOCHUNK

    // ---- l1c = clip([l1^2 * 255/256, l1], 0, 1) ----------------------------
    float l1c[32];
    #pragma unroll
    for (int k = 0; k < 16; ++k) {
        const float v = acc1[k];
        l1c[16 + k] = fminf(fmaxf(v, 0.0f), 1.0f);
        l1c[k] = fminf(v * v * (255.0f / 256.0f), 1.0f);
    }

    // ---- L2 (64x32) fused with Wout[0:64] ----------------------------------
    float accL = 0.0f;
    #pragma unroll 4
    for (int j = 0; j < 64; ++j) {
        const float* wr = wp + O_W2 + j * 32;
        float a = wp[O_B2 + j];
        #pragma unroll
        for (int kq = 0; kq < 8; ++kq) {
            const float4 w = *reinterpret_cast<const float4*>(wr + kq * 4);
            a += w.x * l1c[kq * 4] + w.y * l1c[kq * 4 + 1]
               + w.z * l1c[kq * 4 + 2] + w.w * l1c[kq * 4 + 3];
        }
        a = fminf(fmaxf(a, 0.0f), 1.0f);
        a = a * a * (255.0f / 256.0f);
        accL += wp[O_WOUT + j] * a;
    }

    if (valid) out[s] = wp[O_BOUT] + accA + accP + accL;
}

// ---------------- fallback (round-1 style, self-contained) -------------------
#define FB_BSTR 4580
#define FO_W1B  0
#define FO_W1PA 1056
#define FO_W2   2112
#define FO_WOUT 4160
#define FO_B1B  4480
#define FO_B1PA 4488
#define FO_B2   4496
#define FO_BOUT 4560

__global__ __launch_bounds__(1024, 1)
void layerstacks_fallback(const float* __restrict__ x_base,
                          const float* __restrict__ x_pa,
                          const float* __restrict__ mobility,
                          const int*   __restrict__ ply,
                          const float* __restrict__ W1b,
                          const float* __restrict__ b1b,
                          const float* __restrict__ W1pa,
                          const float* __restrict__ b1pa,
                          const float* __restrict__ W2,
                          const float* __restrict__ b2,
                          const float* __restrict__ Wout,
                          const float* __restrict__ bout,
                          float* __restrict__ out)
{
    __shared__ float lds[NB * FB_BSTR];
    const int tid = threadIdx.x;
    for (int e = tid; e < NB * 1032; e += 1024) {
        int b = e / 1032, r = e - b * 1032;
        int row = r / 129, col = r - row * 129;
        lds[b * FB_BSTR + FO_W1B + row * 132 + col] = W1b[e];
        lds[b * FB_BSTR + FO_W1PA + row * 132 + col] = W1pa[e];
    }
    for (int e = tid; e < NB * 2048; e += 1024) {
        int b = e >> 11, r = e & 2047;
        lds[b * FB_BSTR + FO_W2 + r] = W2[e];
    }
    for (int e = tid; e < NB * 320; e += 1024) {
        int b = e / 320, r = e - b * 320;
        lds[b * FB_BSTR + FO_WOUT + r] = Wout[e];
    }
    if (tid < NB * 8) {
        int b = tid >> 3, r = tid & 7;
        lds[b * FB_BSTR + FO_B1B + r]  = b1b[tid];
        lds[b * FB_BSTR + FO_B1PA + r] = b1pa[tid];
    }
    for (int e = tid; e < NB * 64; e += 1024) {
        int b = e >> 6, r = e & 63;
        lds[b * FB_BSTR + FO_B2 + r] = b2[e];
    }
    if (tid < NB) lds[tid * FB_BSTR + FO_BOUT] = bout[tid];
    __syncthreads();

    const int s = blockIdx.x * 1024 + tid;
    const int idx = ply[s] / 10;
    const float* bk = &lds[idx * FB_BSTR];
    const float mob = fminf(mobility[s] * (7.0f / 255.0f), 1.0f);

    float acc1[16];
    #pragma unroll
    for (int j = 0; j < 8; ++j)
        acc1[j] = bk[FO_B1B + j] + bk[FO_W1B + j * 132 + 128] * mob;
    #pragma unroll
    for (int j = 0; j < 8; ++j)
        acc1[8 + j] = bk[FO_B1PA + j] + bk[FO_W1PA + j * 132 + 128] * mob;
    float accout = bk[FO_BOUT];

    const float4* xb4 = reinterpret_cast<const float4*>(x_base + (size_t)s * 128);
    const float4* xp4 = reinterpret_cast<const float4*>(x_pa   + (size_t)s * 128);
    #pragma unroll 4
    for (int c = 0; c < 32; ++c) {
        const float4 x = xb4[c];
        #pragma unroll
        for (int j = 0; j < 8; ++j) {
            const float4 w = *reinterpret_cast<const float4*>(&bk[FO_W1B + j * 132 + c * 4]);
            acc1[j] += w.x * x.x + w.y * x.y + w.z * x.z + w.w * x.w;
        }
        const float4 wo = *reinterpret_cast<const float4*>(&bk[FO_WOUT + 64 + c * 4]);
        accout += wo.x * x.x + wo.y * x.y + wo.z * x.z + wo.w * x.w;
    }
    #pragma unroll 4
    for (int c = 0; c < 32; ++c) {
        const float4 x = xp4[c];
        #pragma unroll
        for (int j = 0; j < 8; ++j) {
            const float4 w = *reinterpret_cast<const float4*>(&bk[FO_W1PA + j * 132 + c * 4]);
            acc1[8 + j] += w.x * x.x + w.y * x.y + w.z * x.z + w.w * x.w;
        }
        const float4 wo = *reinterpret_cast<const float4*>(&bk[FO_WOUT + 192 + c * 4]);
        accout += wo.x * x.x + wo.y * x.y + wo.z * x.z + wo.w * x.w;
    }
    float l1c[32];
    #pragma unroll
    for (int k = 0; k < 16; ++k) {
        const float v = acc1[k];
        l1c[16 + k] = fminf(fmaxf(v, 0.0f), 1.0f);
        l1c[k] = fminf(v * v * (255.0f / 256.0f), 1.0f);
    }
    #pragma unroll 4
    for (int j = 0; j < 64; ++j) {
        float a = bk[FO_B2 + j];
        #pragma unroll
        for (int k = 0; k < 32; k += 4) {
            const float4 w = *reinterpret_cast<const float4*>(&bk[FO_W2 + j * 32 + k]);
            a += w.x * l1c[k] + w.y * l1c[k + 1] + w.z * l1c[k + 2] + w.w * l1c[k + 3];
        }
        a = fminf(fmaxf(a, 0.0f), 1.0f);
        a = a * a * (255.0f / 256.0f);
        accout += bk[FO_WOUT + j] * a;
    }
    out[s] = accout;
}

extern "C" void kernel_launch(void* const* d_in, const int* in_sizes, int n_in,
                              void* d_out, int out_size, void* d_ws, size_t ws_size,
                              hipStream_t stream) {
    const float* x_base   = (const float*)d_in[0];
    const float* x_pa     = (const float*)d_in[1];
    const float* mobility = (const float*)d_in[2];
    const int*   ply      = (const int*)d_in[3];
    const float* W1b      = (const float*)d_in[4];
    const float* b1b      = (const float*)d_in[5];
    const float* W1pa     = (const float*)d_in[6];
    const float* b1pa     = (const float*)d_in[7];
    const float* W2       = (const float*)d_in[8];
    const float* b2       = (const float*)d_in[9];
    const float* Wout     = (const float*)d_in[10];
    const float* bout     = (const float*)d_in[11];
    float* out = (float*)d_out;

    const int B = in_sizes[3];                      // 262144
    const int padcap = B + NB * 64;
    const size_t ws_needed = (size_t)(WBLOB + 16 + padcap) * sizeof(int);

    if (ws_size >= ws_needed) {
        float* wsF = (float*)d_ws;
        int*   wsI = (int*)d_ws + WBLOB;

        const int blocks1024 = (B + 1023) / 1024;   // 256
        hipMemsetAsync(wsI, 0, 16 * sizeof(int), stream);
        k_init_hist<<<blocks1024, 1024, 0, stream>>>(
            W1b, b1b, W1pa, b1pa, W2, b2, Wout, bout, ply, wsF, wsI, B);
        k_scan<<<1, 64, 0, stream>>>(wsI, B);
        k_scatter<<<blocks1024, 1024, 0, stream>>>(ply, wsI, B);

        const int waves = padcap / 64;
        const int mblocks = (waves + 3) / 4;
        layerstacks_main<<<mblocks, 256, 0, stream>>>(
            x_base, x_pa, mobility, wsF, wsI, out, B);
    } else {
        layerstacks_fallback<<<B / 1024, 1024, 0, stream>>>(
            x_base, x_pa, mobility, ply, W1b, b1b, W1pa, b1pa, W2, b2, Wout, bout, out);
    }
}